// Round 1
// baseline (273.611 us; speedup 1.0000x reference)
//
#include <hip/hip_runtime.h>
#include <hip/hip_bf16.h>

#define NN 30000
#define DIM 128
#define NT 6
#define NE 480000
#define NSLOT 1024
#define NSEG (NT*3*NSLOT)   // 18432
#define CAP 4000000

__device__ __forceinline__ float lrelu(float x){ return x > 0.f ? x : 0.2f*x; }

__global__ void k_init(int* __restrict__ n2s, int* __restrict__ cnt, float* __restrict__ comb){
    int i = blockIdx.x*blockDim.x + threadIdx.x;
    int stride = gridDim.x*blockDim.x;
    for (int j = i; j < NN; j += stride) n2s[j] = 1<<30;
    for (int j = i; j < NSEG; j += stride) cnt[j] = 0;
    for (int j = i; j < NT*NSLOT*DIM; j += stride) comb[j] = 0.f;
}

__global__ void k_slotmap(const int* __restrict__ s, int* __restrict__ n2s){
    int i = blockIdx.x*blockDim.x + threadIdx.x;
    if (i < NSLOT) atomicMin(&n2s[s[i]], i);
}

// h_p = X@W_p, h_c = X@W_c  (32 rows per block; both W in LDS)
__global__ __launch_bounds__(256) void k_gemm(const float* __restrict__ X,
        const float* __restrict__ Wp, const float* __restrict__ Wc,
        float* __restrict__ hp, float* __restrict__ hc){
    __shared__ float WpS[DIM*DIM];
    __shared__ float WcS[DIM*DIM];
    __shared__ float Xs[32*DIM];
    int t = threadIdx.x;
    for (int j = t; j < DIM*DIM; j += 256){ WpS[j] = Wp[j]; WcS[j] = Wc[j]; }
    int row0 = blockIdx.x*32;
    for (int j = t; j < 32*DIM; j += 256){
        int r = row0 + (j>>7);
        Xs[j] = (r < NN) ? X[r*DIM + (j&127)] : 0.f;
    }
    __syncthreads();
    int c4 = (t&31)*4;
    int rg = t>>5;
    float aP[4][4], aC[4][4];
    #pragma unroll
    for (int a=0;a<4;a++)
        #pragma unroll
        for (int bq=0;bq<4;bq++){ aP[a][bq]=0.f; aC[a][bq]=0.f; }
    for (int k=0;k<DIM;k++){
        float4 wp = *(const float4*)&WpS[k*DIM+c4];
        float4 wc = *(const float4*)&WcS[k*DIM+c4];
        #pragma unroll
        for (int ri=0;ri<4;ri++){
            float xv = Xs[(rg*4+ri)*DIM + k];
            aP[ri][0] += xv*wp.x; aP[ri][1] += xv*wp.y; aP[ri][2] += xv*wp.z; aP[ri][3] += xv*wp.w;
            aC[ri][0] += xv*wc.x; aC[ri][1] += xv*wc.y; aC[ri][2] += xv*wc.z; aC[ri][3] += xv*wc.w;
        }
    }
    #pragma unroll
    for (int ri=0;ri<4;ri++){
        int r = row0 + rg*4 + ri;
        if (r < NN){
            *(float4*)&hp[r*DIM+c4] = make_float4(aP[ri][0],aP[ri][1],aP[ri][2],aP[ri][3]);
            *(float4*)&hc[r*DIM+c4] = make_float4(aC[ri][0],aC[ri][1],aC[ri][2],aC[ri][3]);
        }
    }
}

// per-node attention scalars: a = h . att  (wave per node, 4 dots)
__global__ __launch_bounds__(256) void k_att(const float* __restrict__ hp, const float* __restrict__ hc,
        const float* __restrict__ aspv, const float* __restrict__ adpv,
        const float* __restrict__ ascv, const float* __restrict__ adcv,
        float* __restrict__ asp, float* __restrict__ adp,
        float* __restrict__ asc, float* __restrict__ adc){
    int gw  = (blockIdx.x*blockDim.x + threadIdx.x) >> 6;
    int lane = threadIdx.x & 63;
    if (gw >= NN) return;
    float h0 = hp[gw*DIM + lane], h1 = hp[gw*DIM + 64 + lane];
    float c0 = hc[gw*DIM + lane], c1 = hc[gw*DIM + 64 + lane];
    float s0 = h0*aspv[lane] + h1*aspv[64+lane];
    float d0 = h0*adpv[lane] + h1*adpv[64+lane];
    float s1 = c0*ascv[lane] + c1*ascv[64+lane];
    float d1 = c0*adcv[lane] + c1*adcv[64+lane];
    for (int off=32; off; off>>=1){
        s0 += __shfl_down(s0, off);
        d0 += __shfl_down(d0, off);
        s1 += __shfl_down(s1, off);
        d1 += __shfl_down(d1, off);
    }
    if (lane==0){ asp[gw]=s0; adp[gw]=d0; asc[gw]=s1; adc[gw]=d1; }
}

__global__ void k_count(const int* __restrict__ EI, const int* __restrict__ n2s, int* __restrict__ cnt){
    int total = NT*3*NE;
    for (int idx = blockIdx.x*blockDim.x + threadIdx.x; idx < total; idx += gridDim.x*blockDim.x){
        int tg = idx / NE; int e = idx - tg*NE;
        int dst = EI[(tg*2+1)*NE + e];
        int slot = n2s[dst];
        if (slot < NSLOT) atomicAdd(&cnt[tg*NSLOT + slot], 1);
    }
}

__global__ __launch_bounds__(1024) void k_scan(const int* __restrict__ cnt, int* __restrict__ offs, int* __restrict__ cur){
    __shared__ int part[1024];
    int t = threadIdx.x;
    const int PER = NSEG/1024;  // 18
    int base = t*PER;
    int sum = 0;
    for (int j=0;j<PER;j++) sum += cnt[base+j];
    part[t] = sum; __syncthreads();
    for (int off=1; off<1024; off<<=1){
        int add = (t>=off) ? part[t-off] : 0;
        __syncthreads();
        part[t] += add;
        __syncthreads();
    }
    int run = (t==0) ? 0 : part[t-1];
    for (int j=0;j<PER;j++){
        offs[base+j] = run; cur[base+j] = run;
        run += cnt[base+j];
    }
    if (t==1023) offs[NSEG] = run;
}

__global__ void k_fill(const int* __restrict__ EI, const int* __restrict__ n2s,
                       int* __restrict__ cur, int* __restrict__ csr){
    int total = NT*3*NE;
    for (int idx = blockIdx.x*blockDim.x + threadIdx.x; idx < total; idx += gridDim.x*blockDim.x){
        int tg = idx / NE; int e = idx - tg*NE;
        int dst = EI[(tg*2+1)*NE + e];
        int slot = n2s[dst];
        if (slot < NSLOT){
            int src = EI[(tg*2)*NE + e];
            int pos = atomicAdd(&cur[tg*NSLOT + slot], 1);
            if (pos < CAP) csr[pos] = src;
        }
    }
}

// wave per (t, gat, slot) segment
__global__ __launch_bounds__(256) void k_gat(const float* __restrict__ hp, const float* __restrict__ hc,
        const float* __restrict__ asp, const float* __restrict__ adp,
        const float* __restrict__ asc, const float* __restrict__ adc,
        const float* __restrict__ bp, const float* __restrict__ bc,
        const int* __restrict__ s, const int* __restrict__ offs, const int* __restrict__ csr,
        float* __restrict__ comb){
    int gw = (blockIdx.x*blockDim.x + threadIdx.x) >> 6;
    int lane = threadIdx.x & 63;
    if (gw >= NT*2*NSLOT) return;
    int slot = gw & (NSLOT-1);
    int tg2 = gw >> 10;          // t*2 + gat
    int gat = tg2 & 1, t = tg2 >> 1;
    const float* h  = gat ? hc  : hp;
    const float* as = gat ? asc : asp;
    const float* ad = gat ? adc : adp;
    const float* b  = gat ? bc  : bp;
    int v = s[slot];
    int seg = (t*3+gat)*NSLOT + slot;
    int beg = offs[seg], end = offs[seg+1];
    if (beg > CAP) beg = CAP;
    if (end > CAP) end = CAP;
    float adv = ad[v];
    float eself = lrelu(as[v] + adv);
    float m = eself;
    for (int j = beg + lane; j < end; j += 64){
        int src = csr[j];
        m = fmaxf(m, lrelu(as[src] + adv));
    }
    for (int off=32; off; off>>=1) m = fmaxf(m, __shfl_xor(m, off));
    float pself = __expf(eself - m);
    float denom = pself;
    float a0 = pself * h[v*DIM + lane];
    float a1 = pself * h[v*DIM + 64 + lane];
    for (int j = beg; j < end; j++){
        int src = csr[j];
        float p = __expf(lrelu(as[src] + adv) - m);
        denom += p;
        a0 += p * h[src*DIM + lane];
        a1 += p * h[src*DIM + 64 + lane];
    }
    float inv = 1.f/denom;
    float r0 = (a0*inv + b[lane])      * (1.f/3.f);
    float r1 = (a1*inv + b[64+lane])   * (1.f/3.f);
    atomicAdd(&comb[(t*NSLOT+slot)*DIM + lane],      r0);
    atomicAdd(&comb[(t*NSLOT+slot)*DIM + 64 + lane], r1);
}

// wave per (t, slot): SAGE mean + two 128x128 matvecs
__global__ __launch_bounds__(256) void k_sage(const float* __restrict__ X,
        const float* __restrict__ Wl, const float* __restrict__ Wr,
        const float* __restrict__ bl, const float* __restrict__ br,
        const int* __restrict__ s, const int* __restrict__ offs, const int* __restrict__ csr,
        float* __restrict__ comb){
    __shared__ float mean_s[4][DIM];
    __shared__ float xv_s[4][DIM];
    int gw = (blockIdx.x*blockDim.x + threadIdx.x) >> 6;
    int lane = threadIdx.x & 63;
    int wib = threadIdx.x >> 6;
    if (gw >= NT*NSLOT) return;
    int slot = gw & (NSLOT-1), t = gw >> 10;
    int v = s[slot];
    int seg = (t*3+2)*NSLOT + slot;
    int beg = offs[seg], end = offs[seg+1];
    if (beg > CAP) beg = CAP;
    if (end > CAP) end = CAP;
    float m0 = 0.f, m1 = 0.f;
    for (int j = beg; j < end; j++){
        int src = csr[j];
        m0 += X[src*DIM + lane];
        m1 += X[src*DIM + 64 + lane];
    }
    float c = (float)(end - beg); if (c < 1.f) c = 1.f;
    float invc = 1.f/c;
    mean_s[wib][lane]     = m0*invc;
    mean_s[wib][64+lane]  = m1*invc;
    xv_s[wib][lane]       = X[v*DIM + lane];
    xv_s[wib][64+lane]    = X[v*DIM + 64 + lane];
    __syncthreads();
    float a0 = bl[lane]    + br[lane];
    float a1 = bl[64+lane] + br[64+lane];
    for (int k=0;k<DIM;k++){
        float mv = mean_s[wib][k], xv = xv_s[wib][k];
        a0 += mv*Wl[k*DIM + lane]      + xv*Wr[k*DIM + lane];
        a1 += mv*Wl[k*DIM + 64 + lane] + xv*Wr[k*DIM + 64 + lane];
    }
    atomicAdd(&comb[(t*NSLOT+slot)*DIM + lane],      a0*(1.f/3.f));
    atomicAdd(&comb[(t*NSLOT+slot)*DIM + 64 + lane], a1*(1.f/3.f));
}

__global__ void k_gather(const int* __restrict__ s, const int* __restrict__ n2s,
                         const float* __restrict__ comb, float* __restrict__ out){
    int i = blockIdx.x*blockDim.x + threadIdx.x;
    if (i >= NT*NSLOT*DIM) return;
    int d = i & 127;
    int r = (i >> 7) & (NSLOT-1);
    int t = i >> 17;
    int rep = n2s[s[r]];
    out[i] = comb[(t*NSLOT + rep)*DIM + d];
}

extern "C" void kernel_launch(void* const* d_in, const int* in_sizes, int n_in,
                              void* d_out, int out_size, void* d_ws, size_t ws_size,
                              hipStream_t stream) {
    const int*   s    = (const int*)d_in[0];
    const int*   EI   = (const int*)d_in[3];
    const float* X    = (const float*)d_in[4];
    const float* Wp   = (const float*)d_in[5];
    const float* aspv = (const float*)d_in[6];
    const float* adpv = (const float*)d_in[7];
    const float* bp   = (const float*)d_in[8];
    const float* Wc   = (const float*)d_in[9];
    const float* ascv = (const float*)d_in[10];
    const float* adcv = (const float*)d_in[11];
    const float* bc   = (const float*)d_in[12];
    const float* Wl   = (const float*)d_in[13];
    const float* bl   = (const float*)d_in[14];
    const float* Wr   = (const float*)d_in[15];
    const float* br   = (const float*)d_in[16];
    float* out = (float*)d_out;

    char* w = (char*)d_ws;
    float* hp  = (float*)w; w += (size_t)NN*DIM*4;
    float* hc  = (float*)w; w += (size_t)NN*DIM*4;
    float* asp = (float*)w; w += (size_t)NN*4;
    float* adp = (float*)w; w += (size_t)NN*4;
    float* asc = (float*)w; w += (size_t)NN*4;
    float* adc = (float*)w; w += (size_t)NN*4;
    int* n2s  = (int*)w; w += (size_t)NN*4;
    int* cnt  = (int*)w; w += (size_t)NSEG*4;
    int* offs = (int*)w; w += (size_t)(NSEG+4)*4;
    int* cur  = (int*)w; w += (size_t)NSEG*4;
    int* csr  = (int*)w; w += (size_t)CAP*4;
    float* comb = (float*)w; w += (size_t)NT*NSLOT*DIM*4;

    k_init   <<<2048, 256, 0, stream>>>(n2s, cnt, comb);
    k_slotmap<<<4, 256, 0, stream>>>(s, n2s);
    k_gemm   <<<(NN+31)/32, 256, 0, stream>>>(X, Wp, Wc, hp, hc);
    k_att    <<<(NN+3)/4, 256, 0, stream>>>(hp, hc, aspv, adpv, ascv, adcv, asp, adp, asc, adc);
    k_count  <<<2048, 256, 0, stream>>>(EI, n2s, cnt);
    k_scan   <<<1, 1024, 0, stream>>>(cnt, offs, cur);
    k_fill   <<<2048, 256, 0, stream>>>(EI, n2s, cur, csr);
    k_gat    <<<NT*2*NSLOT/4, 256, 0, stream>>>(hp, hc, asp, adp, asc, adc, bp, bc, s, offs, csr, comb);
    k_sage   <<<NT*NSLOT/4, 256, 0, stream>>>(X, Wl, Wr, bl, br, s, offs, csr, comb);
    k_gather <<<NT*NSLOT*DIM/256, 256, 0, stream>>>(s, n2s, comb, out);
}